// Round 4
// baseline (571.590 us; speedup 1.0000x reference)
//
#include <hip/hip_runtime.h>
#include <math.h>

#define B_    16
#define P_    10000
#define NB_   10
#define KBTOT 313      // ceil(P_/32) k-blocks of 32
#define NSMAX 16       // max K-splits

typedef __attribute__((ext_vector_type(8))) short bf16x8;   // 8 bf16 (4 VGPRs)
typedef __attribute__((ext_vector_type(4))) float f32x4;    // MFMA accumulator

static __device__ __forceinline__ unsigned short f2bf(float f) {
    unsigned u = __float_as_uint(f);
    u += 0x7fffu + ((u >> 16) & 1u);
    return (unsigned short)(u >> 16);
}

// ---------------- Kernel 1: T = R(logr) @ S ----------------
// Thread t: p = t>>4, b = t&15. Output Tm2[p][b][12] (48B rows -> aligned
// float4 gathers; 16 b-lanes of one p = 768B contiguous).
__global__ __launch_bounds__(256) void ftoT_kernel(const float* __restrict__ f,
                                                   float* __restrict__ Tm2) {
    int t = blockIdx.x * blockDim.x + threadIdx.x;
    if (t >= B_ * P_) return;
    int p = t >> 4, b = t & 15;
    const float* fp = f + ((size_t)b * P_ + p) * 9;
    float x = fp[0], y = fp[1], z = fp[2];
    float s3 = fp[3], s4 = fp[4], s5 = fp[5], s6 = fp[6], s7 = fp[7], s8 = fp[8];
    float th2 = x * x + y * y + z * z;
    float R00, R01, R02, R10, R11, R12, R20, R21, R22;
    if (th2 == 0.0f) {
        R00 = 1; R01 = 0; R02 = 0; R10 = 0; R11 = 1; R12 = 0; R20 = 0; R21 = 0; R22 = 1;
    } else {
        float theta = sqrtf(th2);
        float inv = 1.0f / theta;
        float kx = x * inv, ky = y * inv, kz = z * inv;
        float st = sinf(theta);
        float omc = 1.0f - cosf(theta);
        R00 = 1.0f - omc * (kx * kx + ky * ky);
        R01 = kx * st - omc * (ky * kz);
        R02 = ky * st + omc * (kx * kz);
        R10 = -kx * st - omc * (ky * kz);
        R11 = 1.0f - omc * (kx * kx + kz * kz);
        R12 = kz * st - omc * (kx * ky);
        R20 = -ky * st + omc * (kx * kz);
        R21 = -kz * st - omc * (kx * ky);
        R22 = 1.0f - omc * (ky * ky + kz * kz);
    }
    float* o = Tm2 + (size_t)t * 12;
    o[0] = R00 * s3 + R01 * s4 + R02 * s5;
    o[1] = R00 * s4 + R01 * s6 + R02 * s7;
    o[2] = R00 * s5 + R01 * s7 + R02 * s8;
    o[3] = R10 * s3 + R11 * s4 + R12 * s5;
    o[4] = R10 * s4 + R11 * s6 + R12 * s7;
    o[5] = R10 * s5 + R11 * s7 + R12 * s8;
    o[6] = R20 * s3 + R21 * s4 + R22 * s5;
    o[7] = R20 * s4 + R21 * s6 + R22 * s7;
    o[8] = R20 * s5 + R21 * s7 + R22 * s8;
    o[9] = 0.0f; o[10] = 0.0f; o[11] = 0.0f;
}

// ------- Kernel 2: bvec + pack one full k-block of B-fragments per block -------
// Block = 512 thr = 32 p x 16 b. nb/vdiff staged coalesced in LDS; fragment
// tile (3 KB) assembled in LDS, written out as 192 coalesced uint4.
__global__ __launch_bounds__(512) void bvec_kernel(const float* __restrict__ Tm2,
                                                   const int* __restrict__ nb,
                                                   const float* __restrict__ vdiff,
                                                   unsigned short* __restrict__ Bf) {
    __shared__ int   s_nb[320];
    __shared__ float s_vd[960];
    __shared__ unsigned short s_B[3 * 64 * 8];   // 3 KB fragment tile
    int tid = threadIdx.x;
    int kb = blockIdx.x;
    int p0 = kb * 32;
    for (int i = tid; i < 320; i += 512) {
        int g = p0 * 10 + i;
        s_nb[i] = (g < P_ * NB_) ? nb[g] : 0;
    }
    for (int i = tid; i < 960; i += 512) {
        int g = p0 * 30 + i;
        s_vd[i] = (g < P_ * NB_ * 3) ? vdiff[g] : 0.0f;
    }
    for (int i = tid; i < 768; i += 512) ((unsigned*)s_B)[i] = 0u;
    __syncthreads();

    int pl = tid >> 4, bl = tid & 15;
    int p = p0 + pl;
    if (p < P_) {
        const float4* Tow = (const float4*)(Tm2 + ((size_t)p * 16 + bl) * 12);
        float4 o0 = Tow[0], o1 = Tow[1], o2v = Tow[2];
        float a0 = 0, a1 = 0, a2 = 0, vs0 = 0, vs1 = 0, vs2 = 0;
#pragma unroll
        for (int nn = 0; nn < NB_; nn++) {
            int idx = s_nb[pl * 10 + nn];
            float v0 = s_vd[pl * 30 + nn * 3 + 0];
            float v1 = s_vd[pl * 30 + nn * 3 + 1];
            float v2 = s_vd[pl * 30 + nn * 3 + 2];
            vs0 += v0; vs1 += v1; vs2 += v2;
            if (idx > 0) {
                const float4* Tp = (const float4*)(Tm2 + ((size_t)(idx - 1) * 16 + bl) * 12);
                float4 q0 = Tp[0], q1 = Tp[1], q2 = Tp[2];
                a0 += q0.x * v0 + q0.y * v1 + q0.z * v2;
                a1 += q0.w * v0 + q1.x * v1 + q1.y * v2;
                a2 += q1.z * v0 + q1.w * v1 + q2.x * v2;
            }
        }
        a0 += o0.x * vs0 + o0.y * vs1 + o0.z * vs2;
        a1 += o0.w * vs0 + o1.x * vs1 + o1.y * vs2;
        a2 += o1.z * vs0 + o1.w * vs1 + o2v.x * vs2;

        int ii = pl & 7, quad = pl >> 3;
        float vals[3] = {a0, a1, a2};
#pragma unroll
        for (int d = 0; d < 3; d++) {
            int j = bl * 3 + d;
            int t = j >> 4;
            int ln = quad * 16 + (j & 15);
            s_B[((size_t)t * 64 + ln) * 8 + ii] = f2bf(vals[d]);
        }
    }
    __syncthreads();
    const uint4* src = (const uint4*)s_B;
    uint4* dst = (uint4*)(Bf + (size_t)kb * (3 * 64 * 8));
    if (tid < 192) dst[tid] = src[tid];
}

// ------- Kernel 3: MFMA GEMM. Wave = 32 rows x 48 cols, reg prefetch. -------
struct Pref {
    float4 x00, x01, x10, x11;   // A rows (2 tiles x 8 floats)
    bf16x8 b0, b1, b2;           // B fragments
};

__global__ __launch_bounds__(256, 4) void gemm_mfma(const float* __restrict__ recon,
                                                    const unsigned short* __restrict__ Bf,
                                                    float* __restrict__ part, int KBC) {
    int l = threadIdx.x & 63;
    int w = threadIdx.x >> 6;
    int r0 = blockIdx.x * 128 + w * 32;      // 32 rows per wave
    int y = blockIdx.y;
    int kb0 = y * KBC;
    int kbend = kb0 + KBC;
    if (kbend > KBTOT) kbend = KBTOT;
    int n = l & 15, quad = l >> 4;
    int rA = r0 + n;       if (rA >= P_) rA = P_ - 1;
    int rB = r0 + 16 + n;  if (rB >= P_) rB = P_ - 1;
    const float* ap0 = recon + (size_t)rA * P_;
    const float* ap1 = recon + (size_t)rB * P_;
    const bf16x8* Bv = (const bf16x8*)Bf;

    f32x4 acc[6];
#pragma unroll
    for (int i = 0; i < 6; i++) acc[i] = (f32x4){0, 0, 0, 0};

    auto loadP = [&](int kb, Pref& Pr) {
        int k = kb * 32 + quad * 8;
        if (k + 8 <= P_) {
            Pr.x00 = *(const float4*)(ap0 + k);
            Pr.x01 = *(const float4*)(ap0 + k + 4);
            Pr.x10 = *(const float4*)(ap1 + k);
            Pr.x11 = *(const float4*)(ap1 + k + 4);
        } else {
            Pr.x00 = Pr.x01 = Pr.x10 = Pr.x11 = make_float4(0, 0, 0, 0);
        }
        size_t o = (size_t)kb * 192 + l;     // 3 tiles * 64 lanes
        Pr.b0 = Bv[o];
        Pr.b1 = Bv[o + 64];
        Pr.b2 = Bv[o + 128];
    };
    auto cvt = [&](float4 lo, float4 hi) -> bf16x8 {
        bf16x8 a;
        a[0] = (short)f2bf(lo.x); a[1] = (short)f2bf(lo.y);
        a[2] = (short)f2bf(lo.z); a[3] = (short)f2bf(lo.w);
        a[4] = (short)f2bf(hi.x); a[5] = (short)f2bf(hi.y);
        a[6] = (short)f2bf(hi.z); a[7] = (short)f2bf(hi.w);
        return a;
    };

    Pref cur, nxt;
    loadP(kb0, cur);
    for (int kb = kb0; kb < kbend; ++kb) {
        int kbn = (kb + 1 < kbend) ? kb + 1 : kb;
        loadP(kbn, nxt);                      // in flight across the MFMAs
        bf16x8 A0 = cvt(cur.x00, cur.x01);
        bf16x8 A1 = cvt(cur.x10, cur.x11);
        acc[0] = __builtin_amdgcn_mfma_f32_16x16x32_bf16(A0, cur.b0, acc[0], 0, 0, 0);
        acc[1] = __builtin_amdgcn_mfma_f32_16x16x32_bf16(A0, cur.b1, acc[1], 0, 0, 0);
        acc[2] = __builtin_amdgcn_mfma_f32_16x16x32_bf16(A0, cur.b2, acc[2], 0, 0, 0);
        acc[3] = __builtin_amdgcn_mfma_f32_16x16x32_bf16(A1, cur.b0, acc[3], 0, 0, 0);
        acc[4] = __builtin_amdgcn_mfma_f32_16x16x32_bf16(A1, cur.b1, acc[4], 0, 0, 0);
        acc[5] = __builtin_amdgcn_mfma_f32_16x16x32_bf16(A1, cur.b2, acc[5], 0, 0, 0);
        cur = nxt;
    }

    // C/D: col = lane&15, row = quad*4 + reg -> float4 store per tile
    float* base = part + (size_t)y * (48 * P_);
    int rs0 = r0 + quad * 4;
    int rs1 = r0 + 16 + quad * 4;
#pragma unroll
    for (int t = 0; t < 3; t++) {
        int j = t * 16 + n;
        if (rs0 < P_) {
            f32x4 a = acc[t];
            *(float4*)(base + (size_t)j * P_ + rs0) = make_float4(a[0], a[1], a[2], a[3]);
        }
        if (rs1 < P_) {
            f32x4 a = acc[3 + t];
            *(float4*)(base + (size_t)j * P_ + rs1) = make_float4(a[0], a[1], a[2], a[3]);
        }
    }
}

// ------- Kernel 4: out[b][r][d] = sum_y part[y][j=b*3+d][r] -------
__global__ __launch_bounds__(256) void reduce_kernel(const float* __restrict__ part,
                                                     float* __restrict__ out, int NS) {
    int i = blockIdx.x * blockDim.x + threadIdx.x;
    if (i >= 48 * P_) return;
    float s = 0.0f;
    for (int z = 0; z < NS; z++) s += part[(size_t)z * (48 * P_) + i];
    int j = i / P_;
    int r = i - j * P_;
    int b = j / 3;
    int d = j - 3 * b;
    out[((size_t)b * P_ + r) * 3 + d] = s;
}

extern "C" void kernel_launch(void* const* d_in, const int* in_sizes, int n_in,
                              void* d_out, int out_size, void* d_ws, size_t ws_size,
                              hipStream_t stream) {
    const float* geo   = (const float*)d_in[0];
    const int*   nb    = (const int*)d_in[1];
    const float* recon = (const float*)d_in[2];
    const float* vdiff = (const float*)d_in[3];
    float* out = (float*)d_out;

    const size_t Tm2F = (size_t)B_ * P_ * 12;             // 1.92M floats
    const size_t BfU  = (size_t)KBTOT * 3 * 64 * 8;       // 480768 ushorts
    const size_t BfF  = (BfU + 1) / 2;
    float*          Tm2  = (float*)d_ws;
    unsigned short* Bf   = (unsigned short*)(Tm2 + Tm2F);
    float*          part = Tm2 + Tm2F + BfF;

    size_t ws_floats = ws_size / 4;
    size_t used = Tm2F + BfF;
    size_t avail = (ws_floats > used) ? (ws_floats - used) : 0;
    int NS = (int)(avail / ((size_t)48 * P_));
    if (NS > NSMAX) NS = NSMAX;
    if (NS < 1) NS = 1;
    int KBC = (KBTOT + NS - 1) / NS;
    int NSeff = (KBTOT + KBC - 1) / KBC;

    int BP = B_ * P_;
    hipLaunchKernelGGL(ftoT_kernel, dim3((BP + 255) / 256), dim3(256), 0, stream, geo, Tm2);
    hipLaunchKernelGGL(bvec_kernel, dim3(KBTOT), dim3(512), 0, stream,
                       Tm2, nb, vdiff, Bf);
    hipLaunchKernelGGL(gemm_mfma, dim3((P_ + 127) / 128, NSeff), dim3(256), 0, stream,
                       recon, Bf, part, KBC);
    hipLaunchKernelGGL(reduce_kernel, dim3((48 * P_ + 255) / 256), dim3(256), 0, stream,
                       part, out, NSeff);
}